// Round 9
// baseline (103.422 us; speedup 1.0000x reference)
//
#include <hip/hip_runtime.h>
#include <math.h>

namespace {

constexpr int B_ = 32;
constexpr int N_ = 16384;
constexpr int M_ = 128;
constexpr int NLOG_ = 80;
constexpr int ROW_ = 86;
constexpr float NEG_ = -1000000000.0f;
constexpr int TILE = 128;          // rows per block
constexpr int TPB = 128;           // one thread per row
constexpr int TPI = N_ / TILE;     // 128 tiles per image
constexpr int BLOCKS = B_ * TPI;   // 4096
constexpr int RSTR = 16;           // floats per tile record
constexpr int NW = TPB / 64;       // 2 waves

__device__ inline float sl1(float d) {
  float ad = fabsf(d);
  return (ad < 1.0f) ? 0.5f * d * d : ad - 0.5f;
}

// Per tile record: [0] tilemax  [1..5] A{nm,bbox,nll,bce1,bce0}  [6] b0all
//                  [7..11] B{nm,bbox,nll,bce1,bce0}  [12] nv
__global__ __launch_bounds__(TPB) void k_main(const float* __restrict__ preds,
                                              const float* __restrict__ targets,
                                              float* __restrict__ recs) {
  // bijective XCD-chunked swizzle (BLOCKS % 8 == 0): each XCD streams a
  // contiguous ~22.5 MB slice of preds through its own L2.
  const int gbid = (blockIdx.x & 7) * (BLOCKS / 8) + (blockIdx.x >> 3);
  const int b = gbid / TPI;
  const int t = threadIdx.x;
  const int lane = t & 63, wid = t >> 6;

  __shared__ float tile[TILE * ROW_];  // 44032 B, whole rows incl. logits
  __shared__ float4 sbox[M_];
  __shared__ float sa2e[M_];  // area + 1e-6 (NaN pads -> inert in strict >)
  __shared__ float sw_[M_];
  __shared__ float scl[M_];
  __shared__ int scnt2[NW];
  __shared__ float smax[NW];
  __shared__ float wacc[NW][12];

  // ---- 1. target loads first (TPB == M_, one target per thread) ----
  const float* tg = targets + (size_t)b * M_ * 5;
  float bx1 = tg[t * 5 + 0], by1 = tg[t * 5 + 1];
  float bx2 = tg[t * 5 + 2], by2 = tg[t * 5 + 3];
  float bcl = tg[t * 5 + 4];

  // ---- 2. coalesced tile stream: 128 rows x 86 floats -> LDS ----
  {
    const float4* src4 = (const float4*)(preds + (size_t)gbid * TILE * ROW_);
    float4* dst4 = (float4*)tile;
    for (int i = t; i < TILE * ROW_ / 4; i += TPB) dst4[i] = src4[i];
  }

  // ---- 3. stable compaction (overlaps the tile stream) ----
  bool tvalid = (bcl != -1.0f);
  unsigned long long ball = __ballot(tvalid);
  if (lane == 0) scnt2[wid] = __popcll(ball);
  int tpos = __popcll(ball & ((1ull << lane) - 1ull));
  __syncthreads();
  const int nv = scnt2[0] + scnt2[1];
  const int nvp = (nv + 3) & ~3;
  if (tvalid) {
    int pos = tpos + (wid ? scnt2[0] : 0);
    sbox[pos] = make_float4(bx1, by1, bx2, by2);
    float ra = (bx2 - bx1) * (by2 - by1);
    sa2e[pos] = ra + 1e-6f;
    sw_[pos] = (ra < 0.01f) ? 1.5f : 1.0f;
    scl[pos] = bcl;
  }
  if (t >= nv && t < nvp) {  // at most 3 pads
    sbox[t] = make_float4(0.f, 0.f, 0.f, 0.f);
    sa2e[t] = __int_as_float(0x7fc00000);  // NaN: never wins strict >
    sw_[t] = 1.0f;
    scl[t] = 0.f;
  }
  __syncthreads();  // tile + compacted targets both ready

  // ---- 4. IoU scan, header straight from LDS ----
  const float* myrow = &tile[t * ROW_];
  float px1 = myrow[0], py1 = myrow[1], px2 = myrow[2], py2 = myrow[3];
  float conf = myrow[4];
  float a1 = (px2 - px1) * (py2 - py1);
  float best = NEG_;
  int bj = 0;
  for (int j = 0; j < nvp; j += 4) {
    float4 tb[4] = {sbox[j], sbox[j + 1], sbox[j + 2], sbox[j + 3]};
    float4 aev = *(const float4*)(&sa2e[j]);
    float ae[4] = {aev.x, aev.y, aev.z, aev.w};
#pragma unroll
    for (int jj = 0; jj < 4; jj++) {
      float x1 = fmaxf(px1, tb[jj].x);
      float y1 = fmaxf(py1, tb[jj].y);
      float x2 = fminf(px2, tb[jj].z);
      float y2 = fminf(py2, tb[jj].w);
      float inter = fmaxf(x2 - x1, 0.f) * fmaxf(y2 - y1, 0.f);
      float u = (a1 + ae[jj]) - inter;  // 1e-6 folded into ae
      float iou = inter * __builtin_amdgcn_rcpf(u);
      bool gt = iou > best;  // strict > = first-occurrence argmax
      best = gt ? iou : best;
      bj = gt ? (j + jj) : bj;
    }
  }

  // ---- 5. tile max ----
  float mx = best;
#pragma unroll
  for (int off = 32; off; off >>= 1) mx = fmaxf(mx, __shfl_xor(mx, off));
  if (lane == 0) smax[wid] = mx;
  __syncthreads();
  const float tilemax = fmaxf(smax[0], smax[1]);

  // ---- 6. losses; softmax logits read from the resident LDS tile ----
  float bce0 = -fmaxf(__logf(1.0f - conf), -100.0f);
  bool mA = (nv > 0) && (best > 0.4f);
  bool mB = (nv > 0) && (best == tilemax);
  float v[11] = {0, 0, 0, 0, 0, 0, 0, 0, 0, 0, 0};
  v[5] = bce0;
  if (mA || mB) {
    float4 gb = sbox[bj];
    float w_ = sw_[bj];
    int ci = (int)scl[bj];
    ci = ci < 0 ? 0 : (ci > NLOG_ - 1 ? NLOG_ - 1 : ci);
    float sb = w_ * (sl1(px1 - gb.x) + sl1(py1 - gb.y) +
                     sl1(px2 - gb.z) + sl1(py2 - gb.w));
    float bce1 = -fmaxf(__logf(conf), -100.0f);
    const float2* l2 = (const float2*)(myrow + 6);
    float se = 0.f;
#pragma unroll 10
    for (int k = 0; k < NLOG_ / 2; k++) {  // one pass, no max-shift: inputs in [0,1)
      float2 lv = l2[k];
      se += __expf(lv.x) + __expf(lv.y);
    }
    float nll = __logf(se) - myrow[6 + ci];
    if (mA) { v[0] = 1.f; v[1] = sb; v[2] = nll; v[3] = bce1; v[4] = bce0; }
    if (mB) { v[6] = 1.f; v[7] = sb; v[8] = nll; v[9] = bce1; v[10] = bce0; }
  }

  // ---- 7. block reduce -> tile record ----
#pragma unroll
  for (int i = 0; i < 11; i++) {
    float x = v[i];
#pragma unroll
    for (int off = 32; off; off >>= 1) x += __shfl_xor(x, off);
    if (lane == 0) wacc[wid][i] = x;
  }
  __syncthreads();
  float* rec = recs + (size_t)gbid * RSTR;
  if (t < 11) rec[1 + t] = wacc[0][t] + wacc[1][t];
  if (t == 12) rec[0] = tilemax;
  if (t == 13) rec[12] = (float)nv;
}

// 32 blocks: block b folds its image's 128 tile records -> limg[b]
__global__ __launch_bounds__(128) void k_fa(const float* __restrict__ recs,
                                            float* __restrict__ limg) {
  const int b = blockIdx.x, t = threadIdx.x;
  const int lane = t & 63, w = t >> 6;
  __shared__ float sbm[2];
  __shared__ float sh[2][12];

  const float4* r4 = (const float4*)(recs + ((size_t)b * TPI + t) * RSTR);
  float4 q0 = r4[0], q1 = r4[1], q2 = r4[2], q3 = r4[3];
  float rmax = q0.x;
  float A0 = q0.y, A1 = q0.z, A2 = q0.w, A3 = q1.x, A4 = q1.y, b0 = q1.z;
  float B0 = q1.w, B1 = q2.x, B2 = q2.y, B3 = q2.z, B4 = q2.w;
  float nv = q3.x;

  // pass 1: global max
  float mx = rmax;
#pragma unroll
  for (int off = 32; off; off >>= 1) mx = fmaxf(mx, __shfl_xor(mx, off));
  if (lane == 0) sbm[w] = mx;
  __syncthreads();
  const float gmax = fmaxf(sbm[0], sbm[1]);

  // pass 2: sums (B gated on tilemax == gmax)
  bool sel = (rmax == gmax);
  float s[12] = {A0, A1, A2, A3, A4, b0,
                 sel ? B0 : 0.f, sel ? B1 : 0.f, sel ? B2 : 0.f,
                 sel ? B3 : 0.f, sel ? B4 : 0.f, 0.f};
#pragma unroll
  for (int i = 0; i < 11; i++) {
    float x = s[i];
#pragma unroll
    for (int off = 32; off; off >>= 1) x += __shfl_xor(x, off);
    if (lane == 0) sh[w][i] = x;
  }
  __syncthreads();
  if (t == 0) {
    float nmA = sh[0][0] + sh[1][0];
    float b0all = sh[0][5] + sh[1][5];
    float loss;
    if (nv == 0.f) {
      loss = b0all * (1.0f / (float)N_);
    } else {
      float nm, bbox, nll, bce1, bce0m;
      if (nmA > 0.f) {
        nm = nmA;
        bbox = sh[0][1] + sh[1][1];
        nll = sh[0][2] + sh[1][2];
        bce1 = sh[0][3] + sh[1][3];
        bce0m = sh[0][4] + sh[1][4];
      } else {
        nm = sh[0][6] + sh[1][6];
        bbox = sh[0][7] + sh[1][7];
        nll = sh[0][8] + sh[1][8];
        bce1 = sh[0][9] + sh[1][9];
        bce0m = sh[0][10] + sh[1][10];
      }
      float nms = fmaxf(nm, 1.0f);
      float bbox_loss = bbox / (nms * 4.0f);
      float cls_loss = nll / nms;
      float m_conf = bce1 / nms;
      float n_u = (float)N_ - nm;
      float u_conf = (b0all - bce0m) / fmaxf(n_u, 1.0f);
      float conf_loss = (n_u > 0.f) ? 0.5f * (m_conf + u_conf) : m_conf;
      loss = 5.0f * bbox_loss + cls_loss + 2.0f * conf_loss;
    }
    limg[b] = loss;
  }
}

__global__ void k_fb(const float* __restrict__ limg, float* __restrict__ out) {
  const int t = threadIdx.x;
  float x = (t < B_) ? limg[t] : 0.f;
#pragma unroll
  for (int off = 32; off; off >>= 1) x += __shfl_xor(x, off);
  if (t == 0) out[0] = x * (1.0f / (float)B_);
}

}  // namespace

extern "C" void kernel_launch(void* const* d_in, const int* in_sizes, int n_in,
                              void* d_out, int out_size, void* d_ws, size_t ws_size,
                              hipStream_t stream) {
  const float* preds = (const float*)d_in[0];
  const float* targets = (const float*)d_in[1];

  char* ws = (char*)d_ws;
  float* recs = (float*)ws;                      // 4096 * 16 * 4 = 256 KB
  float* limg = (float*)(ws + 256 * 1024);       // 32 floats

  k_main<<<dim3(BLOCKS), dim3(TPB), 0, stream>>>(preds, targets, recs);
  k_fa<<<dim3(B_), dim3(128), 0, stream>>>(recs, limg);
  k_fb<<<dim3(1), dim3(64), 0, stream>>>(limg, (float*)d_out);
}

// Round 10
// 88.460 us; speedup vs baseline: 1.1691x; 1.1691x over previous
//
#include <hip/hip_runtime.h>
#include <math.h>

namespace {

constexpr int B_ = 32;
constexpr int N_ = 16384;
constexpr int M_ = 128;
constexpr int NLOG_ = 80;
constexpr int ROW_ = 86;
constexpr float NEG_ = -1000000000.0f;
constexpr int TPB = 256;
constexpr int TILE = 256;              // rows per block (1 row/thread)
constexpr int TPI = N_ / TILE;         // 64 tiles per image
constexpr int BLOCKS = B_ * TPI;       // 2048 -> 8 blocks/CU, 32 waves/CU
constexpr int RSTR = 16;               // floats per tile record
constexpr int NW = TPB / 64;           // 4 waves
constexpr int F4PT = TILE * ROW_ / 4;  // 5504 float4 per tile
constexpr int SH = 8;                  // shdr row stride (floats)

__device__ inline float sl1(float d) {
  float ad = fabsf(d);
  return (ad < 1.0f) ? 0.5f * d * d : ad - 0.5f;
}

// Per tile record: [0] tilemax [1..5] A{nm,bbox,nll,bce1,bce0} [6] b0all
//                  [7..11] B{...} [12] nv
__global__ __launch_bounds__(TPB, 8) void k_main(const float* __restrict__ preds,
                                                 const float* __restrict__ targets,
                                                 float* __restrict__ recs,
                                                 unsigned* __restrict__ counter,
                                                 float* __restrict__ out) {
  // bijective XCD-chunked swizzle (BLOCKS % 8 == 0): each XCD streams a
  // contiguous ~22.5 MB slice of preds through its own L2.
  const int gbid = (blockIdx.x & 7) * (BLOCKS / 8) + (blockIdx.x >> 3);
  const int b = gbid / TPI;
  const int t = threadIdx.x;
  const int lane = t & 63, wid = t >> 6;

  __shared__ float shdr[TILE * SH];  // 8 KB: per-row {x1,y1,x2,y2,conf}
  __shared__ float traw[M_ * 5];
  __shared__ float4 sbox[M_];
  __shared__ float sa2e[M_];  // area + 1e-6 (NaN pads -> inert in strict >)
  __shared__ float sw_[M_];
  __shared__ float scl[M_];
  __shared__ int scnt2[2];
  __shared__ float smax[NW];
  __shared__ float wacc[NW][12];
  __shared__ int s_last;
  __shared__ float limg[B_];

  // ---- 1. target loads issued first ----
  const float* tg = targets + (size_t)b * M_ * 5;
  float tva = tg[t];
  float tvb = tg[t + 256];
  float tvc = (t < 128) ? tg[t + 512] : 0.f;

  // ---- 2. coalesced header stream: dwordx4 through registers, in-flight
  //         extraction of cols 0..4 into shdr (rolling div-mod, ~17 ops/f4) ----
  const float* pt = preds + (size_t)gbid * TILE * ROW_;
  {
    const float4* src4 = (const float4*)pt;
    for (int i = t; i < F4PT; i += TPB) {
      float4 v = src4[i];
      unsigned dw0 = (unsigned)i * 4u;
      unsigned row = dw0 / 86u;
      unsigned col = dw0 - row * 86u;
      float vals[4] = {v.x, v.y, v.z, v.w};
#pragma unroll
      for (int c = 0; c < 4; c++) {
        if (col < 5u) shdr[row * SH + col] = vals[c];
        col++;
        if (col == 86u) { col = 0u; row++; }
      }
    }
  }

  // ---- 3. target staging + stable compaction ----
  traw[t] = tva;
  traw[t + 256] = tvb;
  if (t < 128) traw[t + 512] = tvc;
  __syncthreads();

  float bx1 = 0, by1 = 0, bx2 = 0, by2 = 0, bcl = 0;
  bool tvalid = false;
  int tpos = 0;
  if (t < M_) {
    bx1 = traw[t * 5 + 0]; by1 = traw[t * 5 + 1];
    bx2 = traw[t * 5 + 2]; by2 = traw[t * 5 + 3];
    bcl = traw[t * 5 + 4];
    tvalid = (bcl != -1.0f);
    unsigned long long ball = __ballot(tvalid);
    if (lane == 0) scnt2[wid] = __popcll(ball);
    tpos = __popcll(ball & ((1ull << lane) - 1ull));
  }
  __syncthreads();
  const int nv = scnt2[0] + scnt2[1];
  const int nvp = (nv + 3) & ~3;
  if (t < M_) {
    if (tvalid) {
      int pos = tpos + (wid ? scnt2[0] : 0);
      sbox[pos] = make_float4(bx1, by1, bx2, by2);
      float ra = (bx2 - bx1) * (by2 - by1);
      sa2e[pos] = ra + 1e-6f;
      sw_[pos] = (ra < 0.01f) ? 1.5f : 1.0f;
      scl[pos] = bcl;
    }
    if (t >= nv && t < nvp) {
      sbox[t] = make_float4(0.f, 0.f, 0.f, 0.f);
      sa2e[t] = __int_as_float(0x7fc00000);  // NaN: never wins strict >
      sw_[t] = 1.0f;
      scl[t] = 0.f;
    }
  }
  __syncthreads();  // shdr + compacted targets ready

  // ---- 4. IoU scan, header from shdr ----
  float4 hb = *(const float4*)(&shdr[t * SH]);
  float conf = shdr[t * SH + 4];
  float px1 = hb.x, py1 = hb.y, px2 = hb.z, py2 = hb.w;
  float a1 = (px2 - px1) * (py2 - py1);
  float best = NEG_;
  int bj = 0;
  for (int j = 0; j < nvp; j += 4) {
    float4 tb[4] = {sbox[j], sbox[j + 1], sbox[j + 2], sbox[j + 3]};
    float4 aev = *(const float4*)(&sa2e[j]);
    float ae[4] = {aev.x, aev.y, aev.z, aev.w};
#pragma unroll
    for (int jj = 0; jj < 4; jj++) {
      float x1 = fmaxf(px1, tb[jj].x);
      float y1 = fmaxf(py1, tb[jj].y);
      float x2 = fminf(px2, tb[jj].z);
      float y2 = fminf(py2, tb[jj].w);
      float inter = fmaxf(x2 - x1, 0.f) * fmaxf(y2 - y1, 0.f);
      float u = (a1 + ae[jj]) - inter;  // 1e-6 folded into ae
      float iou = inter * __builtin_amdgcn_rcpf(u);
      bool gt = iou > best;  // strict > = first-occurrence argmax
      best = gt ? iou : best;
      bj = gt ? (j + jj) : bj;
    }
  }

  // ---- 5. tile max ----
  float mx = best;
#pragma unroll
  for (int off = 32; off; off >>= 1) mx = fmaxf(mx, __shfl_xor(mx, off));
  if (lane == 0) smax[wid] = mx;
  __syncthreads();
  const float tilemax = fmaxf(fmaxf(smax[0], smax[1]), fmaxf(smax[2], smax[3]));

  // ---- 6. losses; logits re-read from global (L2-hot: just streamed) ----
  float bce0 = -fmaxf(__logf(1.0f - conf), -100.0f);
  bool mA = (nv > 0) && (best > 0.4f);
  bool mB = (nv > 0) && (best == tilemax);
  float v[11] = {0, 0, 0, 0, 0, 0, 0, 0, 0, 0, 0};
  v[5] = bce0;
  if (mA || mB) {
    float4 gb = sbox[bj];
    float w_ = sw_[bj];
    int ci = (int)scl[bj];
    ci = ci < 0 ? 0 : (ci > NLOG_ - 1 ? NLOG_ - 1 : ci);
    float sb = w_ * (sl1(px1 - gb.x) + sl1(py1 - gb.y) +
                     sl1(px2 - gb.z) + sl1(py2 - gb.w));
    float bce1 = -fmaxf(__logf(conf), -100.0f);
    const float* prow = pt + (size_t)t * ROW_;
    const float2* l2 = (const float2*)(prow + 6);
    float se = 0.f;
#pragma unroll 10
    for (int k = 0; k < NLOG_ / 2; k++) {  // one pass, no max-shift: inputs in [0,1)
      float2 lv = l2[k];
      se += __expf(lv.x) + __expf(lv.y);
    }
    float nll = __logf(se) - prow[6 + ci];
    if (mA) { v[0] = 1.f; v[1] = sb; v[2] = nll; v[3] = bce1; v[4] = bce0; }
    if (mB) { v[6] = 1.f; v[7] = sb; v[8] = nll; v[9] = bce1; v[10] = bce0; }
  }

  // ---- 7. block reduce -> tile record ----
#pragma unroll
  for (int i = 0; i < 11; i++) {
    float x = v[i];
#pragma unroll
    for (int off = 32; off; off >>= 1) x += __shfl_xor(x, off);
    if (lane == 0) wacc[wid][i] = x;
  }
  __syncthreads();
  float* rec = recs + (size_t)gbid * RSTR;
  if (t < 11) rec[1 + t] = wacc[0][t] + wacc[1][t] + wacc[2][t] + wacc[3][t];
  if (t == 12) rec[0] = tilemax;
  if (t == 13) rec[12] = (float)nv;
  __syncthreads();

  // ---- 8. last-block ticket -> in-kernel final reduction (no extra launches).
  // Counter is monotone (never reset): each call adds exactly BLOCKS tickets,
  // so (ticket % BLOCKS) == BLOCKS-1 fires exactly once per call regardless of
  // the counter's (poisoned) start value.
  if (t == 0) {
    __threadfence();
    unsigned tk = atomicAdd(counter, 1u);
    s_last = ((tk & (unsigned)(BLOCKS - 1)) == (unsigned)(BLOCKS - 1)) ? 1 : 0;
  }
  __syncthreads();
  if (!s_last) return;
  __threadfence();

  // 8 lanes per image fold its 64 tile records
  {
    const int im = t >> 3, g = t & 7;
    const float* rb = recs + (size_t)im * TPI * RSTR;
    float aA[6] = {0, 0, 0, 0, 0, 0};
    float bmax = NEG_;
#pragma unroll
    for (int q = 0; q < TPI / 8; q++) {
      const float* r = rb + (size_t)(g + 8 * q) * RSTR;
      bmax = fmaxf(bmax, r[0]);
#pragma unroll
      for (int i = 0; i < 5; i++) aA[i] += r[1 + i];
      aA[5] += r[6];
    }
#pragma unroll
    for (int off = 1; off < 8; off <<= 1) {
      bmax = fmaxf(bmax, __shfl_xor(bmax, off));
#pragma unroll
      for (int i = 0; i < 6; i++) aA[i] += __shfl_xor(aA[i], off);
    }
    float aB[5] = {0, 0, 0, 0, 0};
#pragma unroll
    for (int q = 0; q < TPI / 8; q++) {
      const float* r = rb + (size_t)(g + 8 * q) * RSTR;
      if (r[0] == bmax) {
#pragma unroll
        for (int i = 0; i < 5; i++) aB[i] += r[7 + i];
      }
    }
#pragma unroll
    for (int off = 1; off < 8; off <<= 1) {
#pragma unroll
      for (int i = 0; i < 5; i++) aB[i] += __shfl_xor(aB[i], off);
    }
    if (g == 0) {
      float nvf = rb[12];
      float b0all = aA[5];
      float loss;
      if (nvf == 0.f) {
        loss = b0all * (1.0f / (float)N_);
      } else {
        float nm, bbox, nll, bce1, bce0m;
        if (aA[0] > 0.f) {
          nm = aA[0]; bbox = aA[1]; nll = aA[2]; bce1 = aA[3]; bce0m = aA[4];
        } else {
          nm = aB[0]; bbox = aB[1]; nll = aB[2]; bce1 = aB[3]; bce0m = aB[4];
        }
        float nms = fmaxf(nm, 1.0f);
        float bbox_loss = bbox / (nms * 4.0f);
        float cls_loss = nll / nms;
        float m_conf = bce1 / nms;
        float n_u = (float)N_ - nm;
        float u_conf = (b0all - bce0m) / fmaxf(n_u, 1.0f);
        float conf_loss = (n_u > 0.f) ? 0.5f * (m_conf + u_conf) : m_conf;
        loss = 5.0f * bbox_loss + cls_loss + 2.0f * conf_loss;
      }
      limg[im] = loss;
    }
  }
  __syncthreads();
  if (t < 32) {
    float x = limg[t];
#pragma unroll
    for (int off = 1; off < 32; off <<= 1) x += __shfl_xor(x, off);
    if (t == 0) out[0] = x * (1.0f / (float)B_);
  }
}

}  // namespace

extern "C" void kernel_launch(void* const* d_in, const int* in_sizes, int n_in,
                              void* d_out, int out_size, void* d_ws, size_t ws_size,
                              hipStream_t stream) {
  const float* preds = (const float*)d_in[0];
  const float* targets = (const float*)d_in[1];

  char* ws = (char*)d_ws;
  float* recs = (float*)ws;                         // 2048 * 16 * 4 = 128 KB
  unsigned* counter = (unsigned*)(ws + 131072);     // 4 B, monotone ticket

  k_main<<<dim3(BLOCKS), dim3(TPB), 0, stream>>>(preds, targets, recs, counter,
                                                 (float*)d_out);
}

// Round 12
// 64.529 us; speedup vs baseline: 1.6027x; 1.3709x over previous
//
#include <hip/hip_runtime.h>
#include <math.h>

namespace {

constexpr int B_ = 32;
constexpr int N_ = 16384;
constexpr int M_ = 128;
constexpr int NLOG_ = 80;
constexpr int ROW_ = 86;
constexpr float NEG_ = -1000000000.0f;
constexpr int TPB = 256;
constexpr int RPT = 2;                 // rows per thread
constexpr int BPI = N_ / (TPB * RPT);  // 32 blocks per image
constexpr int BLOCKS = B_ * BPI;       // 1024
constexpr int RSTR = 16;               // floats per block record
constexpr int NW = TPB / 64;           // 4 waves per block

typedef float vf2 __attribute__((ext_vector_type(2)));  // native vector for nt loads

__device__ inline float sl1(float d) {
  float ad = fabsf(d);
  return (ad < 1.0f) ? 0.5f * d * d : ad - 0.5f;
}

// Per block record (RSTR floats):
//  [0] blockmax  [1..5] A{nm,bbox,nll,bce1,bce0}  [6] b0all  [7..11] B{...}  [12] nv
__global__ __launch_bounds__(TPB, 4) void k_main(const float* __restrict__ preds,
                                                 const float* __restrict__ targets,
                                                 float* __restrict__ recs,
                                                 unsigned* __restrict__ counter,
                                                 float* __restrict__ out) {
  const int b = blockIdx.x / BPI;
  const int blk = blockIdx.x % BPI;
  const int t = threadIdx.x;
  const int lane = t & 63, wid = t >> 6;

  __shared__ float traw[M_ * 5];
  __shared__ float4 sbox[M_];
  __shared__ float sa2e[M_];  // raw area + 1e-6 (NaN pads -> inert in strict >)
  __shared__ float sw_[M_];
  __shared__ float scl[M_];
  __shared__ int scnt2[2];
  __shared__ float smax[NW];
  __shared__ float wacc[NW][12];
  __shared__ int s_last;
  __shared__ float limg[B_];

  // ---- 1. target loads issued first (oldest in vmcnt order) ----
  const float* tg = targets + (size_t)b * M_ * 5;
  float tva = tg[t];
  float tvb = tg[t + 256];
  float tvc = (t < 128) ? tg[t + 512] : 0.f;

  // ---- 2. scattered header burst via NON-TEMPORAL loads (bypass L1 alloc;
  //         preds lines are touched once -- no reuse to cache) ----
  const float* pb = preds + (size_t)b * N_ * ROW_;
  const int r0 = blk * (TPB * RPT) + t;
  vf2 h01[RPT], h23[RPT];
  float hc[RPT];
#pragma unroll
  for (int rr = 0; rr < RPT; rr++) {
    const float* p = pb + (size_t)(r0 + rr * TPB) * ROW_;
    h01[rr] = __builtin_nontemporal_load((const vf2*)(p));
    h23[rr] = __builtin_nontemporal_load((const vf2*)(p + 2));
    hc[rr] = __builtin_nontemporal_load(p + 4);
  }

  // ---- 3. compaction preamble (consumes only the target loads) ----
  traw[t] = tva;
  traw[t + 256] = tvb;
  if (t < 128) traw[t + 512] = tvc;
  __syncthreads();

  float bx1 = 0, by1 = 0, bx2 = 0, by2 = 0, bcl = 0;
  bool tvalid = false;
  int tpos = 0;
  if (t < M_) {
    bx1 = traw[t * 5 + 0]; by1 = traw[t * 5 + 1];
    bx2 = traw[t * 5 + 2]; by2 = traw[t * 5 + 3];
    bcl = traw[t * 5 + 4];
    tvalid = (bcl != -1.0f);
    unsigned long long ball = __ballot(tvalid);
    if (lane == 0) scnt2[wid] = __popcll(ball);
    tpos = __popcll(ball & ((1ull << lane) - 1ull));
  }
  __syncthreads();
  const int nv = scnt2[0] + scnt2[1];
  const int nvp = (nv + 3) & ~3;
  if (t < M_) {
    if (tvalid) {
      int pos = tpos + (wid ? scnt2[0] : 0);
      sbox[pos] = make_float4(bx1, by1, bx2, by2);
      float ra = (bx2 - bx1) * (by2 - by1);
      sa2e[pos] = ra + 1e-6f;
      sw_[pos] = (ra < 0.01f) ? 1.5f : 1.0f;
      scl[pos] = bcl;
    }
    if (t >= nv && t < nvp) {
      sbox[t] = make_float4(0.f, 0.f, 0.f, 0.f);
      sa2e[t] = __int_as_float(0x7fc00000);  // NaN: iou=NaN never wins strict >
      sw_[t] = 1.0f;
      scl[t] = 0.f;
    }
  }
  __syncthreads();

  // ---- 4. IoU scan: 8 pair-evals per 5 LDS reads ----
  float a1[RPT], best[RPT];
  int bj[RPT];
#pragma unroll
  for (int rr = 0; rr < RPT; rr++) {
    a1[rr] = (h23[rr].x - h01[rr].x) * (h23[rr].y - h01[rr].y);
    best[rr] = NEG_;
    bj[rr] = 0;
  }
  for (int j = 0; j < nvp; j += 4) {
    float4 tb[4] = {sbox[j], sbox[j + 1], sbox[j + 2], sbox[j + 3]};
    float4 aev = *(const float4*)(&sa2e[j]);
    float ae[4] = {aev.x, aev.y, aev.z, aev.w};
#pragma unroll
    for (int jj = 0; jj < 4; jj++) {
#pragma unroll
      for (int rr = 0; rr < RPT; rr++) {
        float x1 = fmaxf(h01[rr].x, tb[jj].x);
        float y1 = fmaxf(h01[rr].y, tb[jj].y);
        float x2 = fminf(h23[rr].x, tb[jj].z);
        float y2 = fminf(h23[rr].y, tb[jj].w);
        float inter = fmaxf(x2 - x1, 0.f) * fmaxf(y2 - y1, 0.f);
        float u = (a1[rr] + ae[jj]) - inter;  // 1e-6 folded into ae
        float iou = inter * __builtin_amdgcn_rcpf(u);
        bool gt = iou > best[rr];  // strict > = first-occurrence argmax
        best[rr] = gt ? iou : best[rr];
        bj[rr] = gt ? (j + jj) : bj[rr];
      }
    }
  }

  // ---- 5. block max ----
  float mx = fmaxf(best[0], best[RPT - 1]);
#pragma unroll
  for (int off = 32; off; off >>= 1) mx = fmaxf(mx, __shfl_xor(mx, off));
  if (lane == 0) smax[wid] = mx;
  __syncthreads();
  float blockmax = smax[0];
#pragma unroll
  for (int w = 1; w < NW; w++) blockmax = fmaxf(blockmax, smax[w]);

  // ---- 6. losses; divergent one-pass softmax (no max-shift: inputs in [0,1)) ----
  float v[11] = {0, 0, 0, 0, 0, 0, 0, 0, 0, 0, 0};
#pragma unroll
  for (int rr = 0; rr < RPT; rr++) {
    float conf = hc[rr];
    float bce0 = -fmaxf(__logf(1.0f - conf), -100.0f);
    v[5] += bce0;
    bool mA = (nv > 0) && (best[rr] > 0.4f);
    bool mB = (nv > 0) && (best[rr] == blockmax);
    if (mA || mB) {
      int g = bj[rr];
      float4 gb = sbox[g];
      float w_ = sw_[g];
      int ci = (int)scl[g];
      ci = ci < 0 ? 0 : (ci > NLOG_ - 1 ? NLOG_ - 1 : ci);
      float sb = w_ * (sl1(h01[rr].x - gb.x) + sl1(h01[rr].y - gb.y) +
                       sl1(h23[rr].x - gb.z) + sl1(h23[rr].y - gb.w));
      float bce1 = -fmaxf(__logf(conf), -100.0f);
      const float* p = pb + (size_t)(r0 + rr * TPB) * ROW_;
      const vf2* l2 = (const vf2*)(p + 6);
      float se = 0.f;
#pragma unroll 10
      for (int k = 0; k < NLOG_ / 2; k++) {
        vf2 lv = __builtin_nontemporal_load(&l2[k]);
        se += __expf(lv.x) + __expf(lv.y);
      }
      float nll = __logf(se) - __builtin_nontemporal_load(p + 6 + ci);
      if (mA) { v[0] += 1.f; v[1] += sb; v[2] += nll; v[3] += bce1; v[4] += bce0; }
      if (mB) { v[6] += 1.f; v[7] += sb; v[8] += nll; v[9] += bce1; v[10] += bce0; }
    }
  }

  // ---- 7. block reduce 11 values -> per-block record (no atomics) ----
#pragma unroll
  for (int i = 0; i < 11; i++) {
    float x = v[i];
#pragma unroll
    for (int off = 32; off; off >>= 1) x += __shfl_xor(x, off);
    if (lane == 0) wacc[wid][i] = x;
  }
  __syncthreads();
  float* rec = recs + (size_t)blockIdx.x * RSTR;
  if (t < 11) {
    float s = 0.f;
#pragma unroll
    for (int w = 0; w < NW; w++) s += wacc[w][t];
    rec[1 + t] = s;
  }
  if (t == 12) rec[0] = blockmax;
  if (t == 13) rec[12] = (float)nv;
  __syncthreads();

  // ---- 8. last-block ticket -> in-kernel final reduction (no extra launch).
  // Counter is monotone (never reset): each call adds exactly BLOCKS tickets,
  // so (ticket mod BLOCKS) == BLOCKS-1 fires exactly once per call regardless
  // of the (poisoned) start value; 2^32 % 1024 == 0 keeps wraparound safe.
  if (t == 0) {
    __threadfence();
    unsigned tk = atomicAdd(counter, 1u);
    s_last = ((tk & (unsigned)(BLOCKS - 1)) == (unsigned)(BLOCKS - 1)) ? 1 : 0;
  }
  __syncthreads();
  if (!s_last) return;
  __threadfence();

  // 8 lanes per image fold its 32 block records (t>>3 = image, t&7 = group)
  {
    const int im = t >> 3, g = t & 7;
    const float* rb = recs + (size_t)im * BPI * RSTR;
    float aA[6] = {0, 0, 0, 0, 0, 0};
    float bmax = NEG_;
#pragma unroll
    for (int q = 0; q < BPI / 8; q++) {
      const float* r = rb + (size_t)(g + 8 * q) * RSTR;
      bmax = fmaxf(bmax, r[0]);
#pragma unroll
      for (int i = 0; i < 5; i++) aA[i] += r[1 + i];
      aA[5] += r[6];
    }
#pragma unroll
    for (int off = 1; off < 8; off <<= 1) {
      bmax = fmaxf(bmax, __shfl_xor(bmax, off));
#pragma unroll
      for (int i = 0; i < 6; i++) aA[i] += __shfl_xor(aA[i], off);
    }
    float aB[5] = {0, 0, 0, 0, 0};
#pragma unroll
    for (int q = 0; q < BPI / 8; q++) {
      const float* r = rb + (size_t)(g + 8 * q) * RSTR;
      if (r[0] == bmax) {
#pragma unroll
        for (int i = 0; i < 5; i++) aB[i] += r[7 + i];
      }
    }
#pragma unroll
    for (int off = 1; off < 8; off <<= 1) {
#pragma unroll
      for (int i = 0; i < 5; i++) aB[i] += __shfl_xor(aB[i], off);
    }
    if (g == 0) {
      float nvf = rb[12];
      float b0all = aA[5];
      float loss;
      if (nvf == 0.f) {
        loss = b0all * (1.0f / (float)N_);
      } else {
        float nm, bbox, nll, bce1, bce0m;
        if (aA[0] > 0.f) {
          nm = aA[0]; bbox = aA[1]; nll = aA[2]; bce1 = aA[3]; bce0m = aA[4];
        } else {
          nm = aB[0]; bbox = aB[1]; nll = aB[2]; bce1 = aB[3]; bce0m = aB[4];
        }
        float nms = fmaxf(nm, 1.0f);
        float bbox_loss = bbox / (nms * 4.0f);
        float cls_loss = nll / nms;
        float m_conf = bce1 / nms;
        float n_u = (float)N_ - nm;
        float u_conf = (b0all - bce0m) / fmaxf(n_u, 1.0f);
        float conf_loss = (n_u > 0.f) ? 0.5f * (m_conf + u_conf) : m_conf;
        loss = 5.0f * bbox_loss + cls_loss + 2.0f * conf_loss;
      }
      limg[im] = loss;
    }
  }
  __syncthreads();
  if (t < 32) {
    float x = limg[t];
#pragma unroll
    for (int off = 1; off < 32; off <<= 1) x += __shfl_xor(x, off);
    if (t == 0) out[0] = x * (1.0f / (float)B_);
  }
}

}  // namespace

extern "C" void kernel_launch(void* const* d_in, const int* in_sizes, int n_in,
                              void* d_out, int out_size, void* d_ws, size_t ws_size,
                              hipStream_t stream) {
  const float* preds = (const float*)d_in[0];
  const float* targets = (const float*)d_in[1];

  char* ws = (char*)d_ws;
  float* recs = (float*)ws;                      // 1024 * 16 * 4 = 64 KB
  unsigned* counter = (unsigned*)(ws + 65536);   // 4 B, monotone ticket

  k_main<<<dim3(BLOCKS), dim3(TPB), 0, stream>>>(preds, targets, recs, counter,
                                                 (float*)d_out);
}